// Round 6
// baseline (227.181 us; speedup 1.0000x reference)
//
#include <hip/hip_runtime.h>
#include <math.h>

// ---- static config (mirrors reference) ----
#define BB 16
#define AA 3
#define NCC 80
#define WW 76
#define MM 32
#define CELLS_PER_IMG (AA * WW * WW)          // 17328
#define NDECODE (BB * CELLS_PER_IMG * 85)     // 23,566,080
#define NCELLS (BB * CELLS_PER_IMG)           // 277,248
#define N4 (NDECODE / 4)                      // 5,891,520 float4s (N4 % 64 == 0)

typedef float vfloat4 __attribute__((ext_vector_type(4)));

__constant__ float c_anchor[9][2] = {
    {10.f,13.f},{16.f,30.f},{33.f,23.f},{30.f,61.f},{62.f,45.f},
    {59.f,119.f},{116.f,90.f},{156.f,198.f},{373.f,326.f}};

#define LOG2E 1.4426950408889634f

__device__ __forceinline__ float fast_sigmoid(float x) {
    return __builtin_amdgcn_rcpf(1.0f + __builtin_amdgcn_exp2f(-x * LOG2E));
}

__device__ __forceinline__ vfloat4 sig4(vfloat4 v) {
    vfloat4 o;
    o.x = fast_sigmoid(v.x);
    o.y = fast_sigmoid(v.y);
    o.z = fast_sigmoid(v.z);
    o.w = fast_sigmoid(v.w);
    return o;
}

// ---------------------------------------------------------------------------
// Kernel 1: decode — PURE STREAM. load dwordx4, 4x sigmoid, NT store dwordx4.
// NT on this 94 MB stream is VERIFIED across rounds 1/2/4: dirty dec lines in
// cache slow the harness poison fills from 6.7 -> 5.5 TB/s (+26 us of the
// measured window). Box channels get plain sigmoid here; kernel 2 overwrites
// them (stream order) before the harness reads dec.
// ---------------------------------------------------------------------------
__global__ __launch_bounds__(256) void decode_kernel(const vfloat4* __restrict__ in,
                                                     vfloat4* __restrict__ out) {
    unsigned tid  = blockIdx.x * 256u + threadIdx.x;
    unsigned wave = tid >> 6;
    unsigned lane = tid & 63u;
    unsigned i0 = wave * 256u + lane;       // wave-tiled: 1KB contiguous per instr
    unsigned i1 = i0 + 64u;
    unsigned i2 = i0 + 128u;
    unsigned i3 = i0 + 192u;
    const unsigned last = N4 - 1u;

    // clamped unconditional loads -> 4 independent loads in flight
    vfloat4 v0 = in[i0 < last ? i0 : last];
    vfloat4 v1 = in[i1 < last ? i1 : last];
    vfloat4 v2 = in[i2 < last ? i2 : last];
    vfloat4 v3 = in[i3 < last ? i3 : last];

    bool p0 = i0 < N4, p1 = i1 < N4, p2 = i2 < N4, p3 = i3 < N4;  // wave-uniform

    vfloat4 o0 = sig4(v0);
    vfloat4 o1 = sig4(v1);
    vfloat4 o2 = sig4(v2);
    vfloat4 o3 = sig4(v3);

    if (p0) __builtin_nontemporal_store(o0, &out[i0]);
    if (p1) __builtin_nontemporal_store(o1, &out[i1]);
    if (p2) __builtin_nontemporal_store(o2, &out[i2]);
    if (p3) __builtin_nontemporal_store(o3, &out[i3]);
}

// ---------------------------------------------------------------------------
// Kernel 2: per-cell. Recomputes the 4 box values straight from `in`
// (16B gather @ base=85*cell; pred L3-resident since dec bypassed the cache),
// writes them into dec with NORMAL cached stores, uses them for the 32-GT
// max-IoU -> noobj, zeroes obj.
// NORMAL stores here is the round-4 lesson: 1.1M scattered NT dword stores
// (4 per cell, 340B stride) are masked partial-line HBM writes and cost
// ~+19us vs letting L2 coalesce them; the resulting dirty footprint is only
// ~4.4MB, which the round-2 data shows is harmless to the fills (R2's fill
// slowdown came from the 94MB dec stream, not these).
// Formulas bit-identical to the previously passing versions:
//   c0: sig + cell%76   c1: sig + (cell/76)%76
//   c2: exp2(x*log2e) * aw*0.125   c3: exp2(x*log2e) * ah*0.125
// ---------------------------------------------------------------------------
__global__ void noobj_kernel(const float* __restrict__ in, const float* __restrict__ gt,
                             float* __restrict__ dec,
                             float* __restrict__ noobj, float* __restrict__ obj) {
    __shared__ float4 sbox[MM];
    int b = blockIdx.y;
    int t = threadIdx.x;
    if (t < MM) {
        const float* g = gt + (size_t)(b * MM + t) * 6;
        float cx = g[1], cy = g[2], gw = g[3], gh = g[4];
        sbox[t] = make_float4((cx - gw * 0.5f) * 608.0f, (cy - gh * 0.5f) * 608.0f,
                              (cx + gw * 0.5f) * 608.0f, (cy + gh * 0.5f) * 608.0f);
    }
    __syncthreads();
    int n = blockIdx.x * blockDim.x + t;
    if (n >= CELLS_PER_IMG) return;
    size_t idx  = (size_t)b * CELLS_PER_IMG + n;
    size_t base = idx * 85u;

    // gather raw tx,ty,tw,th (independent dword loads; contiguous 16B window)
    float tx = in[base + 0], ty = in[base + 1];
    float tw = in[base + 2], th = in[base + 3];

    unsigned cell = (unsigned)idx;
    unsigned tq  = cell / 76u;
    unsigned gi  = cell - tq * 76u;          // cell % 76
    unsigned tq2 = tq / 76u;
    unsigned gj  = tq - tq2 * 76u;           // (cell/76) % 76
    unsigned a   = tq2 % 3u;                 // anchor index
    float aw = (a == 0u) ? 1.25f  : ((a == 1u) ? 2.0f  : 4.125f); // {10,16,33}*0.125
    float ah = (a == 0u) ? 1.625f : ((a == 1u) ? 3.75f : 2.875f); // {13,30,23}*0.125

    float px = fast_sigmoid(tx) + (float)gi;
    float py = fast_sigmoid(ty) + (float)gj;
    float pw = __builtin_amdgcn_exp2f(tw * LOG2E) * aw;
    float ph = __builtin_amdgcn_exp2f(th * LOG2E) * ah;

    // fix the box channels in dec (cached stores: L2 coalesces the scatter)
    dec[base + 0] = px;
    dec[base + 1] = py;
    dec[base + 2] = pw;
    dec[base + 3] = ph;

    // replicate reference FP order: (val)/W * INPUTW
    float x1 = (px - pw * 0.5f) / 76.0f * 608.0f;
    float y1 = (py - ph * 0.5f) / 76.0f * 608.0f;
    float x2 = (px + pw * 0.5f) / 76.0f * 608.0f;
    float y2 = (py + ph * 0.5f) / 76.0f * 608.0f;
    float area2 = (x2 - x1) * (y2 - y1);
    float best = 0.0f;
#pragma unroll
    for (int m = 0; m < MM; ++m) {
        float4 gb = sbox[m];
        float area1 = (gb.z - gb.x) * (gb.w - gb.y);
        float ltx = fmaxf(gb.x, x1), lty = fmaxf(gb.y, y1);
        float rbx = fminf(gb.z, x2), rby = fminf(gb.w, y2);
        float inter = fmaxf(rbx - ltx, 0.0f) * fmaxf(rby - lty, 0.0f);
        float iou = inter * __builtin_amdgcn_rcpf(area1 + area2 - inter);
        best = fmaxf(best, iou);
    }
    noobj[idx] = (best <= 0.5f) ? 1.0f : 0.0f;
    obj[idx] = 0.0f;
}

// ---------------------------------------------------------------------------
// Kernel 3: per-GT best-anchor argmax. (unchanged; runs after kernel 2)
// ---------------------------------------------------------------------------
__global__ void assign_kernel(const float* __restrict__ gt,
                              float* __restrict__ noobj, float* __restrict__ obj) {
    int r = blockIdx.x * blockDim.x + threadIdx.x;
    if (r >= BB * MM) return;
    const float* g = gt + (size_t)r * 6;
    float cx = g[1], cy = g[2], gw = g[3], gh = g[4];
    float gx1 = (cx - gw * 0.5f) * 608.0f, gy1 = (cy - gh * 0.5f) * 608.0f;
    float gx2 = (cx + gw * 0.5f) * 608.0f, gy2 = (cy + gh * 0.5f) * 608.0f;
    float area_g = (gx2 - gx1) * (gy2 - gy1);
    int best = 0;
    float bestv = -1.0f;
#pragma unroll
    for (int k = 0; k < 9; ++k) {
        float ow = c_anchor[k][0] / 608.0f, oh = c_anchor[k][1] / 608.0f;
        float ax1 = (cx - ow * 0.5f) * 608.0f, ay1 = (cy - oh * 0.5f) * 608.0f;
        float ax2 = (cx + ow * 0.5f) * 608.0f, ay2 = (cy + oh * 0.5f) * 608.0f;
        float ltx = fmaxf(gx1, ax1), lty = fmaxf(gy1, ay1);
        float rbx = fminf(gx2, ax2), rby = fminf(gy2, ay2);
        float inter = fmaxf(rbx - ltx, 0.0f) * fmaxf(rby - lty, 0.0f);
        float area_a = (ax2 - ax1) * (ay2 - ay1);
        float v = inter / (area_g + area_a - inter);
        if (v > bestv) { bestv = v; best = k; }
    }
    if (best < AA) {
        int b = r / MM;
        int gi = (int)(cx * 76.0f);
        int gj = (int)(cy * 76.0f);
        int flat = ((b * AA + best) * WW + gi) * WW + gj;
        obj[flat] = 1.0f;
        noobj[flat] = 0.0f;
    }
}

extern "C" void kernel_launch(void* const* d_in, const int* in_sizes, int n_in,
                              void* d_out, int out_size, void* d_ws, size_t ws_size,
                              hipStream_t stream) {
    const float* pred = (const float*)d_in[0];
    const float* gt   = (const float*)d_in[1];
    float* dec   = (float*)d_out;            // 23,566,080
    float* noobj = dec + NDECODE;            //    277,248
    float* obj   = noobj + NCELLS;           //    277,248
    (void)d_ws; (void)ws_size;               // boxes scratch eliminated

    const int nblocks = (N4 + 1023) / 1024;  // 4 float4s/thread, wave-tiled
    decode_kernel<<<nblocks, 256, 0, stream>>>(
        (const vfloat4*)pred, (vfloat4*)dec);

    dim3 gb((CELLS_PER_IMG + 255) / 256, BB);
    noobj_kernel<<<gb, 256, 0, stream>>>(pred, gt, dec, noobj, obj);

    assign_kernel<<<2, 256, 0, stream>>>(gt, noobj, obj);
}

// Round 7
// 192.425 us; speedup vs baseline: 1.1806x; 1.1806x over previous
//
#include <hip/hip_runtime.h>
#include <math.h>

// ---- static config (mirrors reference) ----
#define BB 16
#define AA 3
#define NCC 80
#define WW 76
#define MM 32
#define CELLS_PER_IMG (AA * WW * WW)          // 17328
#define NDECODE (BB * CELLS_PER_IMG * 85)     // 23,566,080
#define NCELLS (BB * CELLS_PER_IMG)           // 277,248
#define N4 (NDECODE / 4)                      // 5,891,520 float4s

typedef float vfloat4 __attribute__((ext_vector_type(4)));

__constant__ float c_anchor[9][2] = {
    {10.f,13.f},{16.f,30.f},{33.f,23.f},{30.f,61.f},{62.f,45.f},
    {59.f,119.f},{116.f,90.f},{156.f,198.f},{373.f,326.f}};

#define LOG2E 1.4426950408889634f

__device__ __forceinline__ float fast_sigmoid(float x) {
    return __builtin_amdgcn_rcpf(1.0f + __builtin_amdgcn_exp2f(-x * LOG2E));
}

__device__ __forceinline__ vfloat4 sig4(vfloat4 v) {
    vfloat4 o;
    o.x = fast_sigmoid(v.x);
    o.y = fast_sigmoid(v.y);
    o.z = fast_sigmoid(v.z);
    o.w = fast_sigmoid(v.w);
    return o;
}

// Fix the box-channel values inside this lane's float4 (registers only — the
// single NT stream store below writes them; no second store to dec ever).
// Bit-identical math to the passing R1/R6 kernels.
__device__ __forceinline__ void fix_chunk(unsigned i4, const vfloat4 v, vfloat4& o) {
    unsigned b = i4 * 4u;
    unsigned cell = (b + 3u) / 85u;           // largest cell with 85*cell <= b+3
    int s = (int)(cell * 85u) - (int)b;       // window start rel. to b, in (-85, 3]
    if (s >= -3) {                            // chunk intersects a box window
        unsigned t  = cell / 76u;
        unsigned gi = cell - t * 76u;         // cell % 76
        unsigned t2 = t / 76u;
        unsigned gj = t - t2 * 76u;           // (cell/76) % 76
        unsigned a  = t2 % 3u;                // anchor index
        float aw = (a == 0u) ? 1.25f  : ((a == 1u) ? 2.0f  : 4.125f); // {10,16,33}*0.125
        float ah = (a == 0u) ? 1.625f : ((a == 1u) ? 3.75f : 2.875f); // {13,30,23}*0.125
        float q0 = (float)gi, q1 = (float)gj;
        float raw[4] = {v.x, v.y, v.z, v.w};
        float sg[4]  = {o.x, o.y, o.z, o.w};
        float res[4] = {o.x, o.y, o.z, o.w};
#pragma unroll
        for (int j = 0; j < 4; ++j) {
            int k = j - s;                    // channel index if inside window
            if ((unsigned)k < 4u) {
                float e    = __builtin_amdgcn_exp2f(raw[j] * LOG2E);
                float addq = (k == 0) ? q0 : q1;
                float an   = (k == 2) ? aw : ah;
                float val  = (k < 2) ? (sg[j] + addq) : (e * an);
                res[j] = val;
            }
        }
        o.x = res[0]; o.y = res[1]; o.z = res[2]; o.w = res[3];
    }
}

// ---------------------------------------------------------------------------
// Kernel 1: decode. NT pure stream + register-only inline box fix + BATCHED
// boxes scratch writes.
//   - NT on the 94 MB dec stream: VERIFIED (R1/R2/R4/R6 ledger) — ANY cached
//     dirty lines in the dec region slow the harness poison fills 6.7 -> 5.5
//     TB/s (+13 us/fill, 2 fills in window). dec is written ONLY by the NT
//     stream stores here; nothing else ever stores to dec.
//   - boxes: instead of R1's ~16 scattered predicated dword stores per wave
//     (the decode 59-vs-49 gap), lanes 0..12 each own one whole box window in
//     the wave's 1024-float span, re-gather its 4 raw floats from pred
//     (L1-hot: this wave just loaded those lines) and write ONE float4 per
//     cell. boxes lives in ws — cached dirty ws lines are harmless to the
//     fills (R1 evidence).
// ---------------------------------------------------------------------------
__global__ __launch_bounds__(256) void decode_kernel(const vfloat4* __restrict__ in,
                                                     vfloat4* __restrict__ out,
                                                     const float* __restrict__ pred,
                                                     float4* __restrict__ boxes) {
    unsigned tid  = blockIdx.x * 256u + threadIdx.x;
    unsigned wave = tid >> 6;
    unsigned lane = tid & 63u;
    unsigned i0 = wave * 256u + lane;       // wave-tiled: 1KB contiguous per instr
    unsigned i1 = i0 + 64u;
    unsigned i2 = i0 + 128u;
    unsigned i3 = i0 + 192u;
    const unsigned last = N4 - 1u;

    // clamped unconditional loads -> 4 independent loads in flight
    vfloat4 v0 = in[i0 < last ? i0 : last];
    vfloat4 v1 = in[i1 < last ? i1 : last];
    vfloat4 v2 = in[i2 < last ? i2 : last];
    vfloat4 v3 = in[i3 < last ? i3 : last];

    bool p0 = i0 < N4, p1 = i1 < N4, p2 = i2 < N4, p3 = i3 < N4;  // wave-uniform

    vfloat4 o0 = sig4(v0);
    vfloat4 o1 = sig4(v1);
    vfloat4 o2 = sig4(v2);
    vfloat4 o3 = sig4(v3);

    if (p0) fix_chunk(i0, v0, o0);
    if (p1) fix_chunk(i1, v1, o1);
    if (p2) fix_chunk(i2, v2, o2);
    if (p3) fix_chunk(i3, v3, o3);

    if (p0) __builtin_nontemporal_store(o0, &out[i0]);
    if (p1) __builtin_nontemporal_store(o1, &out[i1]);
    if (p2) __builtin_nontemporal_store(o2, &out[i2]);
    if (p3) __builtin_nontemporal_store(o3, &out[i3]);

    // ---- batched boxes writes: lane k owns the k-th box window whose start
    // lies in this wave's float span [wave*1024, wave*1024+1024) ----
    unsigned span = wave * 1024u;
    unsigned c0 = (span + 84u) / 85u;        // first cell with 85*c >= span
    unsigned c  = c0 + lane;
    unsigned ws = c * 85u;                    // window start (float index)
    if (lane < 13u && ws < span + 1024u && c < (unsigned)NCELLS) {
        const float* p = pred + ws;           // 4B-aligned 16B gather, L1/L2-hot
        float t0 = p[0], t1 = p[1], t2v = p[2], t3v = p[3];
        unsigned tq  = c / 76u;
        unsigned gi  = c - tq * 76u;          // cell % 76
        unsigned tq2 = tq / 76u;
        unsigned gj  = tq - tq2 * 76u;        // (cell/76) % 76
        unsigned a   = tq2 % 3u;
        float aw = (a == 0u) ? 1.25f  : ((a == 1u) ? 2.0f  : 4.125f);
        float ah = (a == 0u) ? 1.625f : ((a == 1u) ? 3.75f : 2.875f);
        float px = fast_sigmoid(t0) + (float)gi;
        float py = fast_sigmoid(t1) + (float)gj;
        float pw = __builtin_amdgcn_exp2f(t2v * LOG2E) * aw;
        float ph = __builtin_amdgcn_exp2f(t3v * LOG2E) * ah;
        boxes[c] = make_float4(px, py, pw, ph);  // one dwordx4, 16B-aligned
    }
}

// ---------------------------------------------------------------------------
// Kernel 2: per-cell max-IoU vs the image's 32 GT boxes -> noobj; zero obj.
// R1's light version: reads the dense boxes scratch (coalesced float4, L2/L3
// hot — just written), never touches dec. GT boxes staged in LDS.
// ---------------------------------------------------------------------------
__global__ void noobj_kernel(const float4* __restrict__ boxes, const float* __restrict__ gt,
                             float* __restrict__ noobj, float* __restrict__ obj) {
    __shared__ float4 sbox[MM];
    int b = blockIdx.y;
    int t = threadIdx.x;
    if (t < MM) {
        const float* g = gt + (size_t)(b * MM + t) * 6;
        float cx = g[1], cy = g[2], gw = g[3], gh = g[4];
        sbox[t] = make_float4((cx - gw * 0.5f) * 608.0f, (cy - gh * 0.5f) * 608.0f,
                              (cx + gw * 0.5f) * 608.0f, (cy + gh * 0.5f) * 608.0f);
    }
    __syncthreads();
    int n = blockIdx.x * blockDim.x + t;
    if (n >= CELLS_PER_IMG) return;
    size_t idx = (size_t)b * CELLS_PER_IMG + n;
    float4 pb = boxes[idx];
    float px = pb.x, py = pb.y, pw = pb.z, ph = pb.w;
    // replicate reference FP order: (val)/W * INPUTW
    float x1 = (px - pw * 0.5f) / 76.0f * 608.0f;
    float y1 = (py - ph * 0.5f) / 76.0f * 608.0f;
    float x2 = (px + pw * 0.5f) / 76.0f * 608.0f;
    float y2 = (py + ph * 0.5f) / 76.0f * 608.0f;
    float area2 = (x2 - x1) * (y2 - y1);
    float best = 0.0f;  // iou >= 0 always
#pragma unroll
    for (int m = 0; m < MM; ++m) {
        float4 gb = sbox[m];
        float area1 = (gb.z - gb.x) * (gb.w - gb.y);
        float ltx = fmaxf(gb.x, x1), lty = fmaxf(gb.y, y1);
        float rbx = fminf(gb.z, x2), rby = fminf(gb.w, y2);
        float inter = fmaxf(rbx - ltx, 0.0f) * fmaxf(rby - lty, 0.0f);
        float iou = inter * __builtin_amdgcn_rcpf(area1 + area2 - inter);
        best = fmaxf(best, iou);
    }
    noobj[idx] = (best <= 0.5f) ? 1.0f : 0.0f;
    obj[idx] = 0.0f;
}

// ---------------------------------------------------------------------------
// Kernel 3: per-GT best-anchor argmax. (unchanged; runs after kernel 2)
// ---------------------------------------------------------------------------
__global__ void assign_kernel(const float* __restrict__ gt,
                              float* __restrict__ noobj, float* __restrict__ obj) {
    int r = blockIdx.x * blockDim.x + threadIdx.x;
    if (r >= BB * MM) return;
    const float* g = gt + (size_t)r * 6;
    float cx = g[1], cy = g[2], gw = g[3], gh = g[4];
    float gx1 = (cx - gw * 0.5f) * 608.0f, gy1 = (cy - gh * 0.5f) * 608.0f;
    float gx2 = (cx + gw * 0.5f) * 608.0f, gy2 = (cy + gh * 0.5f) * 608.0f;
    float area_g = (gx2 - gx1) * (gy2 - gy1);
    int best = 0;
    float bestv = -1.0f;
#pragma unroll
    for (int k = 0; k < 9; ++k) {
        float ow = c_anchor[k][0] / 608.0f, oh = c_anchor[k][1] / 608.0f;
        float ax1 = (cx - ow * 0.5f) * 608.0f, ay1 = (cy - oh * 0.5f) * 608.0f;
        float ax2 = (cx + ow * 0.5f) * 608.0f, ay2 = (cy + oh * 0.5f) * 608.0f;
        float ltx = fmaxf(gx1, ax1), lty = fmaxf(gy1, ay1);
        float rbx = fminf(gx2, ax2), rby = fminf(gy2, ay2);
        float inter = fmaxf(rbx - ltx, 0.0f) * fmaxf(rby - lty, 0.0f);
        float area_a = (ax2 - ax1) * (ay2 - ay1);
        float v = inter / (area_g + area_a - inter);
        if (v > bestv) { bestv = v; best = k; }
    }
    if (best < AA) {
        int b = r / MM;  // reference uses row position, not the gt batch column
        int gi = (int)(cx * 76.0f);
        int gj = (int)(cy * 76.0f);
        int flat = ((b * AA + best) * WW + gi) * WW + gj;
        obj[flat] = 1.0f;
        noobj[flat] = 0.0f;
    }
}

extern "C" void kernel_launch(void* const* d_in, const int* in_sizes, int n_in,
                              void* d_out, int out_size, void* d_ws, size_t ws_size,
                              hipStream_t stream) {
    const float* pred = (const float*)d_in[0];
    const float* gt   = (const float*)d_in[1];
    float* dec   = (float*)d_out;            // 23,566,080
    float* noobj = dec + NDECODE;            //    277,248
    float* obj   = noobj + NCELLS;           //    277,248
    float4* boxes = (float4*)d_ws;           // NCELLS float4 = 4.4 MB scratch

    const int nblocks = (N4 + 1023) / 1024;  // 4 float4s/thread, wave-tiled
    decode_kernel<<<nblocks, 256, 0, stream>>>(
        (const vfloat4*)pred, (vfloat4*)dec, pred, boxes);

    dim3 gb((CELLS_PER_IMG + 255) / 256, BB);
    noobj_kernel<<<gb, 256, 0, stream>>>(boxes, gt, noobj, obj);

    assign_kernel<<<2, 256, 0, stream>>>(gt, noobj, obj);
}

// Round 8
// 179.785 us; speedup vs baseline: 1.2636x; 1.0703x over previous
//
#include <hip/hip_runtime.h>
#include <math.h>

// ---- static config (mirrors reference) ----
#define BB 16
#define AA 3
#define NCC 80
#define WW 76
#define MM 32
#define CELLS_PER_IMG (AA * WW * WW)          // 17328
#define NDECODE (BB * CELLS_PER_IMG * 85)     // 23,566,080
#define NCELLS (BB * CELLS_PER_IMG)           // 277,248
#define N4 (NDECODE / 4)                      // 5,891,520 float4s

typedef float vfloat4 __attribute__((ext_vector_type(4)));

__constant__ float c_anchor[9][2] = {
    {10.f,13.f},{16.f,30.f},{33.f,23.f},{30.f,61.f},{62.f,45.f},
    {59.f,119.f},{116.f,90.f},{156.f,198.f},{373.f,326.f}};

#define LOG2E 1.4426950408889634f

__device__ __forceinline__ float fast_sigmoid(float x) {
    return __builtin_amdgcn_rcpf(1.0f + __builtin_amdgcn_exp2f(-x * LOG2E));
}

__device__ __forceinline__ vfloat4 sig4(vfloat4 v) {
    vfloat4 o;
    o.x = fast_sigmoid(v.x);
    o.y = fast_sigmoid(v.y);
    o.z = fast_sigmoid(v.z);
    o.w = fast_sigmoid(v.w);
    return o;
}

// Fix the box-channel values inside this lane's float4 (registers only — the
// single NT stream store writes them; no second store to dec ever).
// Bit-identical math to the passing R1/R6/R7 kernels.
__device__ __forceinline__ void fix_chunk(unsigned i4, const vfloat4 v, vfloat4& o) {
    unsigned b = i4 * 4u;
    unsigned cell = (b + 3u) / 85u;           // largest cell with 85*cell <= b+3
    int s = (int)(cell * 85u) - (int)b;       // window start rel. to b, in (-85, 3]
    if (s >= -3) {                            // chunk intersects a box window
        unsigned t  = cell / 76u;
        unsigned gi = cell - t * 76u;         // cell % 76
        unsigned t2 = t / 76u;
        unsigned gj = t - t2 * 76u;           // (cell/76) % 76
        unsigned a  = t2 % 3u;                // anchor index
        float aw = (a == 0u) ? 1.25f  : ((a == 1u) ? 2.0f  : 4.125f); // {10,16,33}*0.125
        float ah = (a == 0u) ? 1.625f : ((a == 1u) ? 3.75f : 2.875f); // {13,30,23}*0.125
        float q0 = (float)gi, q1 = (float)gj;
        float raw[4] = {v.x, v.y, v.z, v.w};
        float sg[4]  = {o.x, o.y, o.z, o.w};
        float res[4] = {o.x, o.y, o.z, o.w};
#pragma unroll
        for (int j = 0; j < 4; ++j) {
            int k = j - s;                    // channel index if inside window
            if ((unsigned)k < 4u) {
                float e    = __builtin_amdgcn_exp2f(raw[j] * LOG2E);
                float addq = (k == 0) ? q0 : q1;
                float an   = (k == 2) ? aw : ah;
                float val  = (k < 2) ? (sg[j] + addq) : (e * an);
                res[j] = val;
            }
        }
        o.x = res[0]; o.y = res[1]; o.z = res[2]; o.w = res[3];
    }
}

// ---------------------------------------------------------------------------
// Kernel 1: decode + FUSED noobj.
//   - NT on the 94 MB dec stream: VERIFIED (R1/R2/R4/R6/R7 ledger) — any
//     cached dirty lines in the dec region slow the harness poison fills
//     6.8 -> 5.5 TB/s (+13 us/fill, 2 fills in window). dec is written ONLY
//     by the NT stream stores; nothing else ever stores to dec.
//   - Batched per-cell section (R7): lanes 0..12 each own one box window in
//     the wave's 1024-float span, re-gather its 4 raw floats from pred
//     (L1-hot) and compute px/py/pw/ph.
//   - NEW (R8): instead of writing a boxes scratch for a separate noobj
//     kernel, run the 32-GT max-IoU right here (GT xyxy staged in LDS — a
//     block spans <= 2 images, 64 float4s = 1KB) and write noobj[c]/obj[c]
//     directly (cached scattered dwords; 2.2MB dirty — proven harmless to
//     the fills in R1/R7). Eliminates kernel 2, its launch gap, and the
//     4.4MB boxes R+W. The ~450 extra VALU instrs/wave should hide under
//     decode's ~70% memory-stall slack (piggyback probe: if decode's dur is
//     unchanged, the NT-write cap theory is confirmed).
// ---------------------------------------------------------------------------
__global__ __launch_bounds__(256) void decode_kernel(const vfloat4* __restrict__ in,
                                                     vfloat4* __restrict__ out,
                                                     const float* __restrict__ pred,
                                                     const float* __restrict__ gt,
                                                     float* __restrict__ noobj,
                                                     float* __restrict__ obj) {
    // ---- stage GT xyxy for the (<=2) images this block can touch ----
    __shared__ float4 sbox[2 * MM];
    unsigned span_blk = blockIdx.x * 4096u;           // block's float span start
    unsigned cblk0    = (span_blk + 84u) / 85u;       // first cell owned by block
    unsigned bi0      = cblk0 / (unsigned)CELLS_PER_IMG;
    if (threadIdx.x < 64u) {
        unsigned m  = threadIdx.x & 31u;
        unsigned bi = bi0 + (threadIdx.x >> 5);
        if (bi < (unsigned)BB) {
            const float* g = gt + (size_t)(bi * MM + m) * 6;
            float cx = g[1], cy = g[2], gw = g[3], gh = g[4];
            sbox[threadIdx.x] = make_float4((cx - gw * 0.5f) * 608.0f,
                                            (cy - gh * 0.5f) * 608.0f,
                                            (cx + gw * 0.5f) * 608.0f,
                                            (cy + gh * 0.5f) * 608.0f);
        }
    }
    __syncthreads();

    unsigned tid  = blockIdx.x * 256u + threadIdx.x;
    unsigned wave = tid >> 6;
    unsigned lane = tid & 63u;
    unsigned i0 = wave * 256u + lane;       // wave-tiled: 1KB contiguous per instr
    unsigned i1 = i0 + 64u;
    unsigned i2 = i0 + 128u;
    unsigned i3 = i0 + 192u;
    const unsigned last = N4 - 1u;

    // clamped unconditional loads -> 4 independent loads in flight
    vfloat4 v0 = in[i0 < last ? i0 : last];
    vfloat4 v1 = in[i1 < last ? i1 : last];
    vfloat4 v2 = in[i2 < last ? i2 : last];
    vfloat4 v3 = in[i3 < last ? i3 : last];

    bool p0 = i0 < N4, p1 = i1 < N4, p2 = i2 < N4, p3 = i3 < N4;  // wave-uniform

    vfloat4 o0 = sig4(v0);
    vfloat4 o1 = sig4(v1);
    vfloat4 o2 = sig4(v2);
    vfloat4 o3 = sig4(v3);

    if (p0) fix_chunk(i0, v0, o0);
    if (p1) fix_chunk(i1, v1, o1);
    if (p2) fix_chunk(i2, v2, o2);
    if (p3) fix_chunk(i3, v3, o3);

    if (p0) __builtin_nontemporal_store(o0, &out[i0]);
    if (p1) __builtin_nontemporal_store(o1, &out[i1]);
    if (p2) __builtin_nontemporal_store(o2, &out[i2]);
    if (p3) __builtin_nontemporal_store(o3, &out[i3]);

    // ---- batched per-cell section: lane k owns the k-th box window whose
    // start lies in this wave's float span [wave*1024, wave*1024+1024) ----
    unsigned span = wave * 1024u;
    unsigned c0 = (span + 84u) / 85u;         // first cell with 85*c >= span
    unsigned c  = c0 + lane;
    unsigned wstart = c * 85u;                // window start (float index)
    if (lane < 13u && wstart < span + 1024u && c < (unsigned)NCELLS) {
        const float* p = pred + wstart;       // 4B-aligned 16B gather, L1-hot
        float t0 = p[0], t1 = p[1], t2v = p[2], t3v = p[3];
        unsigned tq  = c / 76u;
        unsigned gi  = c - tq * 76u;          // cell % 76
        unsigned tq2 = tq / 76u;
        unsigned gj  = tq - tq2 * 76u;        // (cell/76) % 76
        unsigned a   = tq2 % 3u;
        float aw = (a == 0u) ? 1.25f  : ((a == 1u) ? 2.0f  : 4.125f);
        float ah = (a == 0u) ? 1.625f : ((a == 1u) ? 3.75f : 2.875f);
        float px = fast_sigmoid(t0) + (float)gi;
        float py = fast_sigmoid(t1) + (float)gj;
        float pw = __builtin_amdgcn_exp2f(t2v * LOG2E) * aw;
        float ph = __builtin_amdgcn_exp2f(t3v * LOG2E) * ah;

        // ---- fused noobj: replicate reference FP order: (val)/W * INPUTW ----
        float x1 = (px - pw * 0.5f) / 76.0f * 608.0f;
        float y1 = (py - ph * 0.5f) / 76.0f * 608.0f;
        float x2 = (px + pw * 0.5f) / 76.0f * 608.0f;
        float y2 = (py + ph * 0.5f) / 76.0f * 608.0f;
        float area2 = (x2 - x1) * (y2 - y1);
        unsigned li = (c / (unsigned)CELLS_PER_IMG - bi0) * 32u;  // 0 or 32
        float best = 0.0f;  // iou >= 0 always
#pragma unroll
        for (int m = 0; m < MM; ++m) {
            float4 gb = sbox[li + m];
            float area1 = (gb.z - gb.x) * (gb.w - gb.y);
            float ltx = fmaxf(gb.x, x1), lty = fmaxf(gb.y, y1);
            float rbx = fminf(gb.z, x2), rby = fminf(gb.w, y2);
            float inter = fmaxf(rbx - ltx, 0.0f) * fmaxf(rby - lty, 0.0f);
            float iou = inter * __builtin_amdgcn_rcpf(area1 + area2 - inter);
            best = fmaxf(best, iou);
        }
        noobj[c] = (best <= 0.5f) ? 1.0f : 0.0f;
        obj[c] = 0.0f;
    }
}

// ---------------------------------------------------------------------------
// Kernel 2: per-GT best-anchor argmax. (unchanged; runs after decode's
// noobj/obj writes — stream order guarantees completion.)
// ---------------------------------------------------------------------------
__global__ void assign_kernel(const float* __restrict__ gt,
                              float* __restrict__ noobj, float* __restrict__ obj) {
    int r = blockIdx.x * blockDim.x + threadIdx.x;
    if (r >= BB * MM) return;
    const float* g = gt + (size_t)r * 6;
    float cx = g[1], cy = g[2], gw = g[3], gh = g[4];
    float gx1 = (cx - gw * 0.5f) * 608.0f, gy1 = (cy - gh * 0.5f) * 608.0f;
    float gx2 = (cx + gw * 0.5f) * 608.0f, gy2 = (cy + gh * 0.5f) * 608.0f;
    float area_g = (gx2 - gx1) * (gy2 - gy1);
    int best = 0;
    float bestv = -1.0f;
#pragma unroll
    for (int k = 0; k < 9; ++k) {
        float ow = c_anchor[k][0] / 608.0f, oh = c_anchor[k][1] / 608.0f;
        float ax1 = (cx - ow * 0.5f) * 608.0f, ay1 = (cy - oh * 0.5f) * 608.0f;
        float ax2 = (cx + ow * 0.5f) * 608.0f, ay2 = (cy + oh * 0.5f) * 608.0f;
        float ltx = fmaxf(gx1, ax1), lty = fmaxf(gy1, ay1);
        float rbx = fminf(gx2, ax2), rby = fminf(gy2, ay2);
        float inter = fmaxf(rbx - ltx, 0.0f) * fmaxf(rby - lty, 0.0f);
        float area_a = (ax2 - ax1) * (ay2 - ay1);
        float v = inter / (area_g + area_a - inter);
        if (v > bestv) { bestv = v; best = k; }
    }
    if (best < AA) {
        int b = r / MM;  // reference uses row position, not the gt batch column
        int gi = (int)(cx * 76.0f);
        int gj = (int)(cy * 76.0f);
        int flat = ((b * AA + best) * WW + gi) * WW + gj;
        obj[flat] = 1.0f;
        noobj[flat] = 0.0f;
    }
}

extern "C" void kernel_launch(void* const* d_in, const int* in_sizes, int n_in,
                              void* d_out, int out_size, void* d_ws, size_t ws_size,
                              hipStream_t stream) {
    const float* pred = (const float*)d_in[0];
    const float* gt   = (const float*)d_in[1];
    float* dec   = (float*)d_out;            // 23,566,080
    float* noobj = dec + NDECODE;            //    277,248
    float* obj   = noobj + NCELLS;           //    277,248
    (void)d_ws; (void)ws_size;               // boxes scratch eliminated

    const int nblocks = (N4 + 1023) / 1024;  // 4 float4s/thread, wave-tiled
    decode_kernel<<<nblocks, 256, 0, stream>>>(
        (const vfloat4*)pred, (vfloat4*)dec, pred, gt, noobj, obj);

    assign_kernel<<<2, 256, 0, stream>>>(gt, noobj, obj);
}

// Round 9
// 173.259 us; speedup vs baseline: 1.3112x; 1.0377x over previous
//
#include <hip/hip_runtime.h>
#include <math.h>

// ---- static config (mirrors reference) ----
#define BB 16
#define AA 3
#define NCC 80
#define WW 76
#define MM 32
#define CELLS_PER_IMG (AA * WW * WW)          // 17328
#define NDECODE (BB * CELLS_PER_IMG * 85)     // 23,566,080
#define NCELLS (BB * CELLS_PER_IMG)           // 277,248
#define N4 (NDECODE / 4)                      // 5,891,520 float4s

typedef float vfloat4 __attribute__((ext_vector_type(4)));

__constant__ float c_anchor[9][2] = {
    {10.f,13.f},{16.f,30.f},{33.f,23.f},{30.f,61.f},{62.f,45.f},
    {59.f,119.f},{116.f,90.f},{156.f,198.f},{373.f,326.f}};

#define LOG2E 1.4426950408889634f

__device__ __forceinline__ float fast_sigmoid(float x) {
    return __builtin_amdgcn_rcpf(1.0f + __builtin_amdgcn_exp2f(-x * LOG2E));
}

__device__ __forceinline__ vfloat4 sig4(vfloat4 v) {
    vfloat4 o;
    o.x = fast_sigmoid(v.x);
    o.y = fast_sigmoid(v.y);
    o.z = fast_sigmoid(v.z);
    o.w = fast_sigmoid(v.w);
    return o;
}

// Fix the box-channel values inside this lane's float4 (registers only — the
// single NT stream store writes them; no second store to dec ever).
// Bit-identical math to the passing R1/R6/R7/R8 kernels.
__device__ __forceinline__ void fix_chunk(unsigned i4, const vfloat4 v, vfloat4& o) {
    unsigned b = i4 * 4u;
    unsigned cell = (b + 3u) / 85u;           // largest cell with 85*cell <= b+3
    int s = (int)(cell * 85u) - (int)b;       // window start rel. to b, in (-85, 3]
    if (s >= -3) {                            // chunk intersects a box window
        unsigned t  = cell / 76u;
        unsigned gi = cell - t * 76u;         // cell % 76
        unsigned t2 = t / 76u;
        unsigned gj = t - t2 * 76u;           // (cell/76) % 76
        unsigned a  = t2 % 3u;                // anchor index
        float aw = (a == 0u) ? 1.25f  : ((a == 1u) ? 2.0f  : 4.125f); // {10,16,33}*0.125
        float ah = (a == 0u) ? 1.625f : ((a == 1u) ? 3.75f : 2.875f); // {13,30,23}*0.125
        float q0 = (float)gi, q1 = (float)gj;
        float raw[4] = {v.x, v.y, v.z, v.w};
        float sg[4]  = {o.x, o.y, o.z, o.w};
        float res[4] = {o.x, o.y, o.z, o.w};
#pragma unroll
        for (int j = 0; j < 4; ++j) {
            int k = j - s;                    // channel index if inside window
            if ((unsigned)k < 4u) {
                float e    = __builtin_amdgcn_exp2f(raw[j] * LOG2E);
                float addq = (k == 0) ? q0 : q1;
                float an   = (k == 2) ? aw : ah;
                float val  = (k < 2) ? (sg[j] + addq) : (e * an);
                res[j] = val;
            }
        }
        o.x = res[0]; o.y = res[1]; o.z = res[2]; o.w = res[3];
    }
}

// ---------------------------------------------------------------------------
// Kernel 1: decode + FUSED noobj, wave-parallel IoU tail.
//   - NT on the 94 MB dec stream: VERIFIED (R1-R7 ledger) — any cached dirty
//     lines in the dec region slow the harness poison fills 6.8 -> 5.5 TB/s.
//     dec is written ONLY by the NT stream stores.
//   - R8 lesson: a 13-lane serial 32-iter IoU loop (~550 exec-masked VALU
//     instrs/wave, fully unrolled -> VGPR 76, occupancy 30%) does NOT hide
//     under the stream's memory stall; it added ~20 us of in-phase VALU.
//   - R9: 4 lanes per cell (lanes 0..51). Each lane recomputes the cell box
//     (L1-broadcast loads, ~15 VALU), does 8 IoUs (m = sub+4t), then 2-step
//     __shfl_xor max; sub==0 writes noobj/obj. Tail ~160 instrs/wave, lower
//     unroll -> lower VGPR -> better stream-phase occupancy.
//     Max reordering is exact for non-NaN floats -> bit-identical noobj.
// ---------------------------------------------------------------------------
__global__ __launch_bounds__(256) void decode_kernel(const vfloat4* __restrict__ in,
                                                     vfloat4* __restrict__ out,
                                                     const float* __restrict__ pred,
                                                     const float* __restrict__ gt,
                                                     float* __restrict__ noobj,
                                                     float* __restrict__ obj) {
    // ---- stage GT xyxy for the (<=2) images this block can touch ----
    __shared__ float4 sbox[2 * MM];
    unsigned span_blk = blockIdx.x * 4096u;           // block's float span start
    unsigned cblk0    = (span_blk + 84u) / 85u;       // first cell owned by block
    unsigned bi0      = cblk0 / (unsigned)CELLS_PER_IMG;
    if (threadIdx.x < 64u) {
        unsigned m  = threadIdx.x & 31u;
        unsigned bi = bi0 + (threadIdx.x >> 5);
        if (bi < (unsigned)BB) {
            const float* g = gt + (size_t)(bi * MM + m) * 6;
            float cx = g[1], cy = g[2], gw = g[3], gh = g[4];
            sbox[threadIdx.x] = make_float4((cx - gw * 0.5f) * 608.0f,
                                            (cy - gh * 0.5f) * 608.0f,
                                            (cx + gw * 0.5f) * 608.0f,
                                            (cy + gh * 0.5f) * 608.0f);
        }
    }
    __syncthreads();

    unsigned tid  = blockIdx.x * 256u + threadIdx.x;
    unsigned wave = tid >> 6;
    unsigned lane = tid & 63u;
    unsigned i0 = wave * 256u + lane;       // wave-tiled: 1KB contiguous per instr
    unsigned i1 = i0 + 64u;
    unsigned i2 = i0 + 128u;
    unsigned i3 = i0 + 192u;
    const unsigned last = N4 - 1u;

    // clamped unconditional loads -> 4 independent loads in flight
    vfloat4 v0 = in[i0 < last ? i0 : last];
    vfloat4 v1 = in[i1 < last ? i1 : last];
    vfloat4 v2 = in[i2 < last ? i2 : last];
    vfloat4 v3 = in[i3 < last ? i3 : last];

    bool p0 = i0 < N4, p1 = i1 < N4, p2 = i2 < N4, p3 = i3 < N4;  // wave-uniform

    vfloat4 o0 = sig4(v0);
    vfloat4 o1 = sig4(v1);
    vfloat4 o2 = sig4(v2);
    vfloat4 o3 = sig4(v3);

    if (p0) fix_chunk(i0, v0, o0);
    if (p1) fix_chunk(i1, v1, o1);
    if (p2) fix_chunk(i2, v2, o2);
    if (p3) fix_chunk(i3, v3, o3);

    if (p0) __builtin_nontemporal_store(o0, &out[i0]);
    if (p1) __builtin_nontemporal_store(o1, &out[i1]);
    if (p2) __builtin_nontemporal_store(o2, &out[i2]);
    if (p3) __builtin_nontemporal_store(o3, &out[i3]);

    // ---- fused per-cell noobj: 4 lanes per cell, lanes 0..51 ----
    unsigned span = wave * 1024u;
    unsigned c0 = (span + 84u) / 85u;         // first cell with 85*c >= span
    unsigned j   = lane >> 2;                 // cell slot 0..15 (13 used)
    unsigned sub = lane & 3u;                 // GT quarter 0..3
    unsigned c  = c0 + j;
    unsigned wstart = c * 85u;                // window start (float index)
    if (j < 13u && wstart < span + 1024u && c < (unsigned)NCELLS) {
        const float* p = pred + wstart;       // L1-hot; 4 lanes broadcast-load
        float t0 = p[0], t1 = p[1], t2v = p[2], t3v = p[3];
        unsigned tq  = c / 76u;
        unsigned gi  = c - tq * 76u;          // cell % 76
        unsigned tq2 = tq / 76u;
        unsigned gj  = tq - tq2 * 76u;        // (cell/76) % 76
        unsigned a   = tq2 % 3u;
        float aw = (a == 0u) ? 1.25f  : ((a == 1u) ? 2.0f  : 4.125f);
        float ah = (a == 0u) ? 1.625f : ((a == 1u) ? 3.75f : 2.875f);
        float px = fast_sigmoid(t0) + (float)gi;
        float py = fast_sigmoid(t1) + (float)gj;
        float pw = __builtin_amdgcn_exp2f(t2v * LOG2E) * aw;
        float ph = __builtin_amdgcn_exp2f(t3v * LOG2E) * ah;

        // replicate reference FP order: (val)/W * INPUTW
        float x1 = (px - pw * 0.5f) / 76.0f * 608.0f;
        float y1 = (py - ph * 0.5f) / 76.0f * 608.0f;
        float x2 = (px + pw * 0.5f) / 76.0f * 608.0f;
        float y2 = (py + ph * 0.5f) / 76.0f * 608.0f;
        float area2 = (x2 - x1) * (y2 - y1);
        unsigned li = (c / (unsigned)CELLS_PER_IMG - bi0) * 32u;  // 0 or 32
        float best = 0.0f;  // iou >= 0 always
#pragma unroll
        for (int t = 0; t < 8; ++t) {         // this lane's 8 GTs: m = sub + 4t
            float4 gb = sbox[li + sub + 4u * t];
            float area1 = (gb.z - gb.x) * (gb.w - gb.y);
            float ltx = fmaxf(gb.x, x1), lty = fmaxf(gb.y, y1);
            float rbx = fminf(gb.z, x2), rby = fminf(gb.w, y2);
            float inter = fmaxf(rbx - ltx, 0.0f) * fmaxf(rby - lty, 0.0f);
            float iou = inter * __builtin_amdgcn_rcpf(area1 + area2 - inter);
            best = fmaxf(best, iou);
        }
        // 2-step butterfly max within the 4-lane group (exact for non-NaN)
        best = fmaxf(best, __shfl_xor(best, 1));
        best = fmaxf(best, __shfl_xor(best, 2));
        if (sub == 0u) {
            noobj[c] = (best <= 0.5f) ? 1.0f : 0.0f;
            obj[c] = 0.0f;
        }
    }
}

// ---------------------------------------------------------------------------
// Kernel 2: per-GT best-anchor argmax. (unchanged; runs after decode's
// noobj/obj writes — stream order guarantees completion.)
// ---------------------------------------------------------------------------
__global__ void assign_kernel(const float* __restrict__ gt,
                              float* __restrict__ noobj, float* __restrict__ obj) {
    int r = blockIdx.x * blockDim.x + threadIdx.x;
    if (r >= BB * MM) return;
    const float* g = gt + (size_t)r * 6;
    float cx = g[1], cy = g[2], gw = g[3], gh = g[4];
    float gx1 = (cx - gw * 0.5f) * 608.0f, gy1 = (cy - gh * 0.5f) * 608.0f;
    float gx2 = (cx + gw * 0.5f) * 608.0f, gy2 = (cy + gh * 0.5f) * 608.0f;
    float area_g = (gx2 - gx1) * (gy2 - gy1);
    int best = 0;
    float bestv = -1.0f;
#pragma unroll
    for (int k = 0; k < 9; ++k) {
        float ow = c_anchor[k][0] / 608.0f, oh = c_anchor[k][1] / 608.0f;
        float ax1 = (cx - ow * 0.5f) * 608.0f, ay1 = (cy - oh * 0.5f) * 608.0f;
        float ax2 = (cx + ow * 0.5f) * 608.0f, ay2 = (cy + oh * 0.5f) * 608.0f;
        float ltx = fmaxf(gx1, ax1), lty = fmaxf(gy1, ay1);
        float rbx = fminf(gx2, ax2), rby = fminf(gy2, ay2);
        float inter = fmaxf(rbx - ltx, 0.0f) * fmaxf(rby - lty, 0.0f);
        float area_a = (ax2 - ax1) * (ay2 - ay1);
        float v = inter / (area_g + area_a - inter);
        if (v > bestv) { bestv = v; best = k; }
    }
    if (best < AA) {
        int b = r / MM;  // reference uses row position, not the gt batch column
        int gi = (int)(cx * 76.0f);
        int gj = (int)(cy * 76.0f);
        int flat = ((b * AA + best) * WW + gi) * WW + gj;
        obj[flat] = 1.0f;
        noobj[flat] = 0.0f;
    }
}

extern "C" void kernel_launch(void* const* d_in, const int* in_sizes, int n_in,
                              void* d_out, int out_size, void* d_ws, size_t ws_size,
                              hipStream_t stream) {
    const float* pred = (const float*)d_in[0];
    const float* gt   = (const float*)d_in[1];
    float* dec   = (float*)d_out;            // 23,566,080
    float* noobj = dec + NDECODE;            //    277,248
    float* obj   = noobj + NCELLS;           //    277,248
    (void)d_ws; (void)ws_size;               // no scratch needed

    const int nblocks = (N4 + 1023) / 1024;  // 4 float4s/thread, wave-tiled
    decode_kernel<<<nblocks, 256, 0, stream>>>(
        (const vfloat4*)pred, (vfloat4*)dec, pred, gt, noobj, obj);

    assign_kernel<<<2, 256, 0, stream>>>(gt, noobj, obj);
}